// Round 5
// baseline (515.948 us; speedup 1.0000x reference)
//
#include <hip/hip_runtime.h>
#include <hip/hip_bf16.h>

// RelPosBlock: LN1 -> QKV -> per-head QK-LN -> attn(+rel_bias) -> proj(+LS1, resid)
//              -> LN2 -> FC1+GELU -> FC2(+LS2, resid)
// B=4 N=1024 C=1024 H=16 D=64 Hid=4096, all inputs f32, output f32.

typedef __attribute__((ext_vector_type(8))) short short8;   // 8 bf16 (4 VGPR)
typedef __attribute__((ext_vector_type(4))) float f32x4;

#define MFMA16(a, b, c) __builtin_amdgcn_mfma_f32_16x16x32_bf16(a, b, c, 0, 0, 0)

static __device__ __forceinline__ unsigned short f2b(float f) {
  union { __hip_bfloat16 h; unsigned short u; } cv;
  cv.h = __float2bfloat16(f);
  return cv.u;
}

// async global->LDS, 16B per lane; lds base must be wave-uniform (HW adds lane*16)
static __device__ __forceinline__ void gld16(const unsigned short* g,
                                             unsigned short* l) {
  __builtin_amdgcn_global_load_lds(
      (const __attribute__((address_space(1))) void*)g,
      (__attribute__((address_space(3))) void*)l, 16, 0, 0);
}

// ---------------- f32 -> bf16 convert (grid-stride, float4) ----------------
__global__ void cvt_bf16_kernel(const float* __restrict__ in,
                                unsigned short* __restrict__ out, int n4) {
  int i = blockIdx.x * blockDim.x + threadIdx.x;
  int stride = gridDim.x * blockDim.x;
  for (; i < n4; i += stride) {
    float4 v = reinterpret_cast<const float4*>(in)[i];
    ushort4 o;
    o.x = f2b(v.x); o.y = f2b(v.y); o.z = f2b(v.z); o.w = f2b(v.w);
    reinterpret_cast<ushort4*>(out)[i] = o;
  }
}

// ---------------- LayerNorm over C=1024, f32 in -> bf16 out ----------------
__global__ __launch_bounds__(256) void ln_kernel(const float* __restrict__ x,
                                                 const float* __restrict__ w,
                                                 const float* __restrict__ b,
                                                 unsigned short* __restrict__ out) {
  int row = blockIdx.x, tid = threadIdx.x;
  const float* xr = x + (size_t)row * 1024;
  float4 v = reinterpret_cast<const float4*>(xr)[tid];
  float s = v.x + v.y + v.z + v.w;
  float s2 = v.x * v.x + v.y * v.y + v.z * v.z + v.w * v.w;
  for (int off = 1; off < 64; off <<= 1) {
    s += __shfl_xor(s, off);
    s2 += __shfl_xor(s2, off);
  }
  __shared__ float red[8];
  int wid = tid >> 6;
  if ((tid & 63) == 0) { red[wid] = s; red[4 + wid] = s2; }
  __syncthreads();
  s = red[0] + red[1] + red[2] + red[3];
  s2 = red[4] + red[5] + red[6] + red[7];
  float mean = s * (1.f / 1024.f);
  float rs = rsqrtf(s2 * (1.f / 1024.f) - mean * mean + 1e-5f);
  float4 wv = reinterpret_cast<const float4*>(w)[tid];
  float4 bv = reinterpret_cast<const float4*>(b)[tid];
  ushort4 o;
  o.x = f2b((v.x - mean) * rs * wv.x + bv.x);
  o.y = f2b((v.y - mean) * rs * wv.y + bv.y);
  o.z = f2b((v.z - mean) * rs * wv.z + bv.z);
  o.w = f2b((v.w - mean) * rs * wv.w + bv.w);
  reinterpret_cast<ushort4*>(out + (size_t)row * 1024)[tid] = o;
}

// ------------- per-head Q/K LayerNorm (D=64) + pack Q,K,Vt bf16 -------------
// qkv f32 [4096][3072], j = qkvi*1024 + h*64 + d
// Q,K: [B*H, N, 64] bf16 (Q pre-scaled by D^-0.5); Vt: [B*H, 64, N] bf16
__global__ __launch_bounds__(256) void qkpack_kernel(
    const float* __restrict__ qkv, const float* __restrict__ qw,
    const float* __restrict__ qb, const float* __restrict__ kw,
    const float* __restrict__ kb_, unsigned short* __restrict__ Q,
    unsigned short* __restrict__ K, unsigned short* __restrict__ Vt) {
  int wid = blockIdx.x * 4 + (threadIdx.x >> 6);
  int lane = threadIdx.x & 63;
  int m = wid >> 4;  // 0..4095
  int h = wid & 15;
  int b = m >> 10, n = m & 1023;
  const float* base = qkv + (size_t)m * 3072 + h * 64 + lane;
  float q = base[0], k = base[1024], v = base[2048];
  float qs = q, qs2 = q * q, ks = k, ks2 = k * k;
  for (int off = 1; off < 64; off <<= 1) {
    qs += __shfl_xor(qs, off); qs2 += __shfl_xor(qs2, off);
    ks += __shfl_xor(ks, off); ks2 += __shfl_xor(ks2, off);
  }
  float qm = qs * (1.f / 64.f), qv = qs2 * (1.f / 64.f) - qm * qm;
  float km = ks * (1.f / 64.f), kv = ks2 * (1.f / 64.f) - km * km;
  float qn = (q - qm) * rsqrtf(qv + 1e-5f) * qw[lane] + qb[lane];
  float kn = (k - km) * rsqrtf(kv + 1e-5f) * kw[lane] + kb_[lane];
  int bh = b * 16 + h;
  Q[((size_t)bh * 1024 + n) * 64 + lane] = f2b(qn * 0.125f);
  K[((size_t)bh * 1024 + n) * 64 + lane] = f2b(kn);
  Vt[((size_t)bh * 64 + lane) * 1024 + n] = f2b(v);
}

// ---------------- flash attention with rel_bias ----------------
// grid: [B*H*16], block 256 (4 waves x 16 q-rows). 32-key tiles.
__global__ __launch_bounds__(256) void attn_kernel(
    const unsigned short* __restrict__ Q, const unsigned short* __restrict__ K,
    const unsigned short* __restrict__ Vt, const float* __restrict__ rb,
    unsigned short* __restrict__ O) {
  __shared__ unsigned short Ks[32][80];     // 32 keys x 64 chans (+pad)
  __shared__ unsigned short Vs[64][40];     // 64 d x 32 keys (+pad)
  __shared__ unsigned short Ps[4][16][40];  // per-wave P tile 16x32 (+pad)
  int bid = blockIdx.x;
  int qt = bid & 15, bh = bid >> 4;
  int h = bh & 15, b = bh >> 4;
  int q0 = qt * 64;
  int tid = threadIdx.x, lane = tid & 63, w = tid >> 6;
  int lg = lane >> 4, lr = lane & 15;

  short8 qf[2];
  {
    int qrow = q0 + w * 16 + lr;
    const unsigned short* qp = Q + ((size_t)bh * 1024 + qrow) * 64;
    qf[0] = *reinterpret_cast<const short8*>(qp + lg * 8);
    qf[1] = *reinterpret_cast<const short8*>(qp + 32 + lg * 8);
  }
  f32x4 o[4] = {};
  float mrow[4], lrow[4];
  for (int i = 0; i < 4; i++) { mrow[i] = -1e30f; lrow[i] = 0.f; }
  const float* rbh = rb + (size_t)h * 1024 * 1024;

  for (int kt = 0; kt < 32; kt++) {
    __syncthreads();  // protect restage vs previous iteration's reads
    {
      int r = tid >> 3, c = (tid & 7) * 8;
      *reinterpret_cast<short8*>(&Ks[r][c]) =
          *reinterpret_cast<const short8*>(K + ((size_t)bh * 1024 + kt * 32 + r) * 64 + c);
      int d = tid >> 2, j = (tid & 3) * 8;
      *reinterpret_cast<short8*>(&Vs[d][j]) =
          *reinterpret_cast<const short8*>(Vt + ((size_t)bh * 64 + d) * 1024 + kt * 32 + j);
    }
    __syncthreads();
    // S = Q K^T  (two 16-key subtiles)
    f32x4 s[2] = {};
    for (int t = 0; t < 2; t++) {
      short8 kf0 = *reinterpret_cast<const short8*>(&Ks[t * 16 + lr][lg * 8]);
      short8 kf1 = *reinterpret_cast<const short8*>(&Ks[t * 16 + lr][32 + lg * 8]);
      s[t] = MFMA16(qf[0], kf0, s[t]);
      s[t] = MFMA16(qf[1], kf1, s[t]);
    }
    // online softmax (C-frag: col=lane&15, row=(lane>>4)*4+i)
    int myrow = q0 + w * 16 + lg * 4;
    for (int i = 0; i < 4; i++) {
      float s0 = s[0][i] + rbh[(size_t)(myrow + i) * 1024 + kt * 32 + lr];
      float s1 = s[1][i] + rbh[(size_t)(myrow + i) * 1024 + kt * 32 + 16 + lr];
      float mx = fmaxf(s0, s1);
      for (int off = 1; off < 16; off <<= 1) mx = fmaxf(mx, __shfl_xor(mx, off));
      float mnew = fmaxf(mrow[i], mx);
      float corr = __expf(mrow[i] - mnew);
      float p0 = __expf(s0 - mnew), p1 = __expf(s1 - mnew);
      float ps = p0 + p1;
      for (int off = 1; off < 16; off <<= 1) ps += __shfl_xor(ps, off);
      lrow[i] = lrow[i] * corr + ps;
      mrow[i] = mnew;
      for (int nd = 0; nd < 4; nd++) o[nd][i] *= corr;
      Ps[w][lg * 4 + i][lr] = f2b(p0);
      Ps[w][lg * 4 + i][16 + lr] = f2b(p1);
    }
    __syncthreads();  // make cross-lane P writes visible (and order vs ds reads)
    // O += P V  (A-frag of P: row=lane&15, k=(lane>>4)*8+i)
    short8 pa = *reinterpret_cast<const short8*>(&Ps[w][lr][lg * 8]);
    for (int nd = 0; nd < 4; nd++) {
      short8 vf = *reinterpret_cast<const short8*>(&Vs[nd * 16 + lr][lg * 8]);
      o[nd] = MFMA16(pa, vf, o[nd]);
    }
  }
  // write O: [B,N,H*64] bf16
  for (int i = 0; i < 4; i++) {
    float inv = 1.f / lrow[i];
    int n = q0 + w * 16 + lg * 4 + i;
    size_t base = ((size_t)(b * 1024 + n)) * 1024 + h * 64;
    for (int nd = 0; nd < 4; nd++) O[base + nd * 16 + lr] = f2b(o[nd][i] * inv);
  }
}

// ---------------- bf16 GEMM, B^T layout: out[m][n] = sum_k A[m][k]*W[n][k] ----------------
// m97-style: 128x128 tile, BK=32, linear LDS [128][32], global_load_lds width-16 staging.
// MODE 0: outF = acc                       (QKV)
// MODE 1: outF = resid + gamma*(acc+bias)  (proj / FC2 epilogue)
// MODE 2: outB = bf16(gelu(acc+bias))      (FC1)
template <int MODE>
__global__ __launch_bounds__(256) void gemm_bt(
    const unsigned short* __restrict__ A, const unsigned short* __restrict__ W,
    const float* __restrict__ bias, const float* __restrict__ resid,
    const float* __restrict__ gamma, float* __restrict__ outF,
    unsigned short* __restrict__ outB, int M, int Nn, int Kd) {
  __shared__ unsigned short As[128 * 32];  // linear, 64 B/row (no pad: DMA dest)
  __shared__ unsigned short Bs[128 * 32];
  int tid = threadIdx.x;
  int lane = tid & 63, wv = tid >> 6;
  int wm = wv >> 1, wn = wv & 1;
  int lg = lane >> 4, lr = lane & 15;
  int m0 = blockIdx.y * 128, n0 = blockIdx.x * 128;
  f32x4 acc[4][4] = {};
  // staging: per wave 4 chunks of 1024B (16 rows). lane -> (row, 16B col) in chunk.
  int lrow = lane >> 2;         // 0..15
  int lcol = (lane & 3) * 8;    // elem col: 0,8,16,24
  int c0 = wv * 16, c1 = 64 + wv * 16;  // wave's chunk start rows
  const unsigned short* Ab = A + (size_t)(m0 + lrow) * Kd + lcol;
  const unsigned short* Wb = W + (size_t)(n0 + lrow) * Kd + lcol;
  for (int k0 = 0; k0 < Kd; k0 += 32) {
    __syncthreads();  // prior ds_reads done before overwrite
    gld16(Ab + (size_t)c0 * Kd + k0, &As[c0 * 32]);
    gld16(Ab + (size_t)c1 * Kd + k0, &As[c1 * 32]);
    gld16(Wb + (size_t)c0 * Kd + k0, &Bs[c0 * 32]);
    gld16(Wb + (size_t)c1 * Kd + k0, &Bs[c1 * 32]);
    __syncthreads();  // compiler drains vmcnt(0) before barrier -> LDS valid
    short8 af[4], bf[4];
    for (int i = 0; i < 4; i++)
      af[i] = *reinterpret_cast<const short8*>(&As[(wm * 64 + i * 16 + lr) * 32 + lg * 8]);
    for (int i = 0; i < 4; i++)
      bf[i] = *reinterpret_cast<const short8*>(&Bs[(wn * 64 + i * 16 + lr) * 32 + lg * 8]);
    for (int mi = 0; mi < 4; mi++)
      for (int ni = 0; ni < 4; ni++)
        acc[mi][ni] = MFMA16(af[mi], bf[ni], acc[mi][ni]);
  }
  int row0 = m0 + wm * 64, col0 = n0 + wn * 64;
  for (int mi = 0; mi < 4; mi++)
    for (int ni = 0; ni < 4; ni++) {
      int col = col0 + ni * 16 + lr;
      int rbase = row0 + mi * 16 + lg * 4;
      for (int i = 0; i < 4; i++) {
        int row = rbase + i;
        float v = acc[mi][ni][i];
        if (MODE == 0) {
          outF[(size_t)row * Nn + col] = v;
        } else if (MODE == 1) {
          outF[(size_t)row * Nn + col] =
              resid[(size_t)row * Nn + col] + gamma[col] * (v + bias[col]);
        } else {
          float t = v + bias[col];
          float g = 0.5f * t * (1.f + erff(t * 0.70710678f));
          outB[(size_t)row * Nn + col] = f2b(g);
        }
      }
    }
}

extern "C" void kernel_launch(void* const* d_in, const int* in_sizes, int n_in,
                              void* d_out, int out_size, void* d_ws, size_t ws_size,
                              hipStream_t stream) {
  const float* x      = (const float*)d_in[0];
  const float* relb   = (const float*)d_in[1];
  const float* qkv_w  = (const float*)d_in[2];
  const float* qnw    = (const float*)d_in[3];
  const float* qnb    = (const float*)d_in[4];
  const float* knw    = (const float*)d_in[5];
  const float* knb    = (const float*)d_in[6];
  const float* proj_w = (const float*)d_in[7];
  const float* proj_b = (const float*)d_in[8];
  const float* n1w    = (const float*)d_in[9];
  const float* n1b    = (const float*)d_in[10];
  const float* n2w    = (const float*)d_in[11];
  const float* n2b    = (const float*)d_in[12];
  const float* fc1_w  = (const float*)d_in[13];
  const float* fc1_b  = (const float*)d_in[14];
  const float* fc2_w  = (const float*)d_in[15];
  const float* fc2_b  = (const float*)d_in[16];
  const float* ls1    = (const float*)d_in[17];
  const float* ls2    = (const float*)d_in[18];
  float* out = (float*)d_out;

  char* ws = (char*)d_ws;
  size_t off = 0;
  auto take = [&](size_t bytes) {
    char* p = ws + off;
    off += (bytes + 255) & ~(size_t)255;
    return p;
  };
  unsigned short* h     = (unsigned short*)take((size_t)4096 * 1024 * 2);
  unsigned short* wqkv  = (unsigned short*)take((size_t)3072 * 1024 * 2);
  unsigned short* wproj = (unsigned short*)take((size_t)1024 * 1024 * 2);
  unsigned short* wfc1  = (unsigned short*)take((size_t)4096 * 1024 * 2);
  unsigned short* wfc2  = (unsigned short*)take((size_t)4096 * 1024 * 2);
  float*          qkvb  = (float*)take((size_t)4096 * 3072 * 4);
  unsigned short* Q     = (unsigned short*)take((size_t)64 * 1024 * 64 * 2);
  unsigned short* Kb    = (unsigned short*)take((size_t)64 * 1024 * 64 * 2);
  unsigned short* Vt    = (unsigned short*)take((size_t)64 * 64 * 1024 * 2);
  unsigned short* ao    = (unsigned short*)take((size_t)4096 * 1024 * 2);
  float*          x1    = (float*)take((size_t)4096 * 1024 * 4);
  unsigned short* h2 = h;                      // reuse (h dead after QKV GEMM)
  unsigned short* m1 = (unsigned short*)qkvb;  // reuse (qkv dead after pack; 32MB<=48MB)

  cvt_bf16_kernel<<<1024, 256, 0, stream>>>(qkv_w, wqkv, 3072 * 1024 / 4);
  cvt_bf16_kernel<<<1024, 256, 0, stream>>>(proj_w, wproj, 1024 * 1024 / 4);
  cvt_bf16_kernel<<<1024, 256, 0, stream>>>(fc1_w, wfc1, 4096 * 1024 / 4);
  cvt_bf16_kernel<<<1024, 256, 0, stream>>>(fc2_w, wfc2, 4096 * 1024 / 4);

  ln_kernel<<<4096, 256, 0, stream>>>(x, n1w, n1b, h);
  gemm_bt<0><<<dim3(24, 32), 256, 0, stream>>>(h, wqkv, nullptr, nullptr, nullptr,
                                               qkvb, nullptr, 4096, 3072, 1024);
  qkpack_kernel<<<16384, 256, 0, stream>>>(qkvb, qnw, qnb, knw, knb, Q, Kb, Vt);
  attn_kernel<<<1024, 256, 0, stream>>>(Q, Kb, Vt, relb, ao);
  gemm_bt<1><<<dim3(8, 32), 256, 0, stream>>>(ao, wproj, proj_b, x, ls1, x1,
                                              nullptr, 4096, 1024, 1024);
  ln_kernel<<<4096, 256, 0, stream>>>(x1, n2w, n2b, h2);
  gemm_bt<2><<<dim3(32, 32), 256, 0, stream>>>(h2, wfc1, fc1_b, nullptr, nullptr,
                                               nullptr, m1, 4096, 4096, 1024);
  gemm_bt<1><<<dim3(8, 32), 256, 0, stream>>>(m1, wfc2, fc2_b, x1, ls2, out,
                                              nullptr, 4096, 1024, 4096);
}

// Round 7
// 475.840 us; speedup vs baseline: 1.0843x; 1.0843x over previous
//
#include <hip/hip_runtime.h>
#include <hip/hip_bf16.h>

// RelPosBlock: LN1 -> QKV -> per-head QK-LN -> attn(+rel_bias) -> proj(+LS1, resid)
//              -> LN2 -> FC1+GELU -> FC2(+LS2, resid)
// B=4 N=1024 C=1024 H=16 D=64 Hid=4096, all inputs f32, output f32.

typedef __attribute__((ext_vector_type(8))) short short8;   // 8 bf16 (4 VGPR)
typedef __attribute__((ext_vector_type(4))) float f32x4;

#define MFMA16(a, b, c) __builtin_amdgcn_mfma_f32_16x16x32_bf16(a, b, c, 0, 0, 0)

static __device__ __forceinline__ unsigned short f2b(float f) {
  union { __hip_bfloat16 h; unsigned short u; } cv;
  cv.h = __float2bfloat16(f);
  return cv.u;
}

// async global->LDS, 16B per lane; lds base must be wave-uniform (HW adds lane*16)
static __device__ __forceinline__ void gld16(const unsigned short* g,
                                             unsigned short* l) {
  __builtin_amdgcn_global_load_lds(
      (const __attribute__((address_space(1))) void*)g,
      (__attribute__((address_space(3))) void*)l, 16, 0, 0);
}

// explicit DMA drain: do NOT trust __syncthreads to emit vmcnt(0) when the
// stage is separated from the barrier by compute (round-6 race post-mortem).
static __device__ __forceinline__ void drain_dma_then_barrier() {
  asm volatile("s_waitcnt vmcnt(0)" ::: "memory");
  __builtin_amdgcn_sched_barrier(0);
  __syncthreads();
}

// ---------------- f32 -> bf16 convert (grid-stride, float4) ----------------
__global__ void cvt_bf16_kernel(const float* __restrict__ in,
                                unsigned short* __restrict__ out, int n4) {
  int i = blockIdx.x * blockDim.x + threadIdx.x;
  int stride = gridDim.x * blockDim.x;
  for (; i < n4; i += stride) {
    float4 v = reinterpret_cast<const float4*>(in)[i];
    ushort4 o;
    o.x = f2b(v.x); o.y = f2b(v.y); o.z = f2b(v.z); o.w = f2b(v.w);
    reinterpret_cast<ushort4*>(out)[i] = o;
  }
}

// ---------------- LayerNorm over C=1024, f32 in -> bf16 out ----------------
__global__ __launch_bounds__(256) void ln_kernel(const float* __restrict__ x,
                                                 const float* __restrict__ w,
                                                 const float* __restrict__ b,
                                                 unsigned short* __restrict__ out) {
  int row = blockIdx.x, tid = threadIdx.x;
  const float* xr = x + (size_t)row * 1024;
  float4 v = reinterpret_cast<const float4*>(xr)[tid];
  float s = v.x + v.y + v.z + v.w;
  float s2 = v.x * v.x + v.y * v.y + v.z * v.z + v.w * v.w;
  for (int off = 1; off < 64; off <<= 1) {
    s += __shfl_xor(s, off);
    s2 += __shfl_xor(s2, off);
  }
  __shared__ float red[8];
  int wid = tid >> 6;
  if ((tid & 63) == 0) { red[wid] = s; red[4 + wid] = s2; }
  __syncthreads();
  s = red[0] + red[1] + red[2] + red[3];
  s2 = red[4] + red[5] + red[6] + red[7];
  float mean = s * (1.f / 1024.f);
  float rs = rsqrtf(s2 * (1.f / 1024.f) - mean * mean + 1e-5f);
  float4 wv = reinterpret_cast<const float4*>(w)[tid];
  float4 bv = reinterpret_cast<const float4*>(b)[tid];
  ushort4 o;
  o.x = f2b((v.x - mean) * rs * wv.x + bv.x);
  o.y = f2b((v.y - mean) * rs * wv.y + bv.y);
  o.z = f2b((v.z - mean) * rs * wv.z + bv.z);
  o.w = f2b((v.w - mean) * rs * wv.w + bv.w);
  reinterpret_cast<ushort4*>(out + (size_t)row * 1024)[tid] = o;
}

// ------------- per-head Q/K LayerNorm (D=64) + pack Q,K,Vt bf16 -------------
// qkv f32 [4096][3072], j = qkvi*1024 + h*64 + d
// Q,K: [B*H, N, 64] bf16 (Q pre-scaled by D^-0.5); Vt: [B*H, 64, N] bf16
__global__ __launch_bounds__(256) void qkpack_kernel(
    const float* __restrict__ qkv, const float* __restrict__ qw,
    const float* __restrict__ qb, const float* __restrict__ kw,
    const float* __restrict__ kb_, unsigned short* __restrict__ Q,
    unsigned short* __restrict__ K, unsigned short* __restrict__ Vt) {
  int wid = blockIdx.x * 4 + (threadIdx.x >> 6);
  int lane = threadIdx.x & 63;
  int m = wid >> 4;  // 0..4095
  int h = wid & 15;
  int b = m >> 10, n = m & 1023;
  const float* base = qkv + (size_t)m * 3072 + h * 64 + lane;
  float q = base[0], k = base[1024], v = base[2048];
  float qs = q, qs2 = q * q, ks = k, ks2 = k * k;
  for (int off = 1; off < 64; off <<= 1) {
    qs += __shfl_xor(qs, off); qs2 += __shfl_xor(qs2, off);
    ks += __shfl_xor(ks, off); ks2 += __shfl_xor(ks2, off);
  }
  float qm = qs * (1.f / 64.f), qv = qs2 * (1.f / 64.f) - qm * qm;
  float km = ks * (1.f / 64.f), kv = ks2 * (1.f / 64.f) - km * km;
  float qn = (q - qm) * rsqrtf(qv + 1e-5f) * qw[lane] + qb[lane];
  float kn = (k - km) * rsqrtf(kv + 1e-5f) * kw[lane] + kb_[lane];
  int bh = b * 16 + h;
  Q[((size_t)bh * 1024 + n) * 64 + lane] = f2b(qn * 0.125f);
  K[((size_t)bh * 1024 + n) * 64 + lane] = f2b(kn);
  Vt[((size_t)bh * 64 + lane) * 1024 + n] = f2b(v);
}

// ---------------- flash attention with rel_bias ----------------
// grid: [B*H*16], block 256 (4 waves x 16 q-rows). 32-key tiles.
__global__ __launch_bounds__(256) void attn_kernel(
    const unsigned short* __restrict__ Q, const unsigned short* __restrict__ K,
    const unsigned short* __restrict__ Vt, const float* __restrict__ rb,
    unsigned short* __restrict__ O) {
  __shared__ unsigned short Ks[32][80];     // 32 keys x 64 chans (+pad)
  __shared__ unsigned short Vs[64][40];     // 64 d x 32 keys (+pad)
  __shared__ unsigned short Ps[4][16][40];  // per-wave P tile 16x32 (+pad)
  int bid = blockIdx.x;
  int qt = bid & 15, bh = bid >> 4;
  int h = bh & 15, b = bh >> 4;
  int q0 = qt * 64;
  int tid = threadIdx.x, lane = tid & 63, w = tid >> 6;
  int lg = lane >> 4, lr = lane & 15;

  short8 qf[2];
  {
    int qrow = q0 + w * 16 + lr;
    const unsigned short* qp = Q + ((size_t)bh * 1024 + qrow) * 64;
    qf[0] = *reinterpret_cast<const short8*>(qp + lg * 8);
    qf[1] = *reinterpret_cast<const short8*>(qp + 32 + lg * 8);
  }
  f32x4 o[4] = {};
  float mrow[4], lrow[4];
  for (int i = 0; i < 4; i++) { mrow[i] = -1e30f; lrow[i] = 0.f; }
  const float* rbh = rb + (size_t)h * 1024 * 1024;

  for (int kt = 0; kt < 32; kt++) {
    __syncthreads();  // protect restage vs previous iteration's reads
    {
      int r = tid >> 3, c = (tid & 7) * 8;
      *reinterpret_cast<short8*>(&Ks[r][c]) =
          *reinterpret_cast<const short8*>(K + ((size_t)bh * 1024 + kt * 32 + r) * 64 + c);
      int d = tid >> 2, j = (tid & 3) * 8;
      *reinterpret_cast<short8*>(&Vs[d][j]) =
          *reinterpret_cast<const short8*>(Vt + ((size_t)bh * 64 + d) * 1024 + kt * 32 + j);
    }
    __syncthreads();
    // S = Q K^T  (two 16-key subtiles)
    f32x4 s[2] = {};
    for (int t = 0; t < 2; t++) {
      short8 kf0 = *reinterpret_cast<const short8*>(&Ks[t * 16 + lr][lg * 8]);
      short8 kf1 = *reinterpret_cast<const short8*>(&Ks[t * 16 + lr][32 + lg * 8]);
      s[t] = MFMA16(qf[0], kf0, s[t]);
      s[t] = MFMA16(qf[1], kf1, s[t]);
    }
    // online softmax (C-frag: col=lane&15, row=(lane>>4)*4+i)
    int myrow = q0 + w * 16 + lg * 4;
    for (int i = 0; i < 4; i++) {
      float s0 = s[0][i] + rbh[(size_t)(myrow + i) * 1024 + kt * 32 + lr];
      float s1 = s[1][i] + rbh[(size_t)(myrow + i) * 1024 + kt * 32 + 16 + lr];
      float mx = fmaxf(s0, s1);
      for (int off = 1; off < 16; off <<= 1) mx = fmaxf(mx, __shfl_xor(mx, off));
      float mnew = fmaxf(mrow[i], mx);
      float corr = __expf(mrow[i] - mnew);
      float p0 = __expf(s0 - mnew), p1 = __expf(s1 - mnew);
      float ps = p0 + p1;
      for (int off = 1; off < 16; off <<= 1) ps += __shfl_xor(ps, off);
      lrow[i] = lrow[i] * corr + ps;
      mrow[i] = mnew;
      for (int nd = 0; nd < 4; nd++) o[nd][i] *= corr;
      Ps[w][lg * 4 + i][lr] = f2b(p0);
      Ps[w][lg * 4 + i][16 + lr] = f2b(p1);
    }
    __syncthreads();  // make cross-lane P writes visible (and order vs ds reads)
    // O += P V  (A-frag of P: row=lane&15, k=(lane>>4)*8+i)
    short8 pa = *reinterpret_cast<const short8*>(&Ps[w][lr][lg * 8]);
    for (int nd = 0; nd < 4; nd++) {
      short8 vf = *reinterpret_cast<const short8*>(&Vs[nd * 16 + lr][lg * 8]);
      o[nd] = MFMA16(pa, vf, o[nd]);
    }
  }
  // write O: [B,N,H*64] bf16
  for (int i = 0; i < 4; i++) {
    float inv = 1.f / lrow[i];
    int n = q0 + w * 16 + lg * 4 + i;
    size_t base = ((size_t)(b * 1024 + n)) * 1024 + h * 64;
    for (int nd = 0; nd < 4; nd++) O[base + nd * 16 + lr] = f2b(o[nd][i] * inv);
  }
}

// ---------------- bf16 GEMM, B^T layout: out[m][n] = sum_k A[m][k]*W[n][k] ----------------
// BM x 128 tile, BK=32, 2-phase double-buffered linear LDS + global_load_lds w16,
// bijective XCD swizzle (grid must be %8==0; launched 1-D).
// Explicit vmcnt(0) drain before each publishing barrier (round-6 race fix).
// MODE 0: outF = acc                       (QKV)
// MODE 1: outF = resid + gamma*(acc+bias)  (proj / FC2 epilogue)
// MODE 2: outB = bf16(gelu(acc+bias))      (FC1)
template <int MODE, int BM>
__global__ __launch_bounds__(256) void gemm_bt(
    const unsigned short* __restrict__ A, const unsigned short* __restrict__ W,
    const float* __restrict__ bias, const float* __restrict__ resid,
    const float* __restrict__ gamma, float* __restrict__ outF,
    unsigned short* __restrict__ outB, int M, int Nn, int Kd) {
  constexpr int BN = 128;
  constexpr int MI = BM / 32;      // 16x16 A-frags per wave (wave covers BM/2 rows)
  constexpr int ACH = BM / 16;     // 1024B A-chunks per K-step
  constexpr int TCH = ACH + BN / 16;  // total chunks (16 or 12)
  constexpr int CPW = TCH / 4;     // chunks per wave (4 or 3)
  __shared__ unsigned short S[2][(BM + BN) * 32];  // A rows then W rows, 64B/row
  int tid = threadIdx.x;
  int lane = tid & 63, wv = tid >> 6;
  int wm = wv >> 1, wn = wv & 1;
  int lg = lane >> 4, lr = lane & 15;
  // XCD swizzle: contiguous chunk of block-ids per XCD (gridDim.x % 8 == 0)
  int nbx = Nn >> 7;
  int cpx = gridDim.x >> 3;
  int swz = (blockIdx.x & 7) * cpx + (blockIdx.x >> 3);
  int m0 = (swz / nbx) * BM, n0 = (swz % nbx) * BN;
  f32x4 acc[MI][4] = {};
  int lrow = lane >> 2;        // 0..15 within chunk
  int lcol = (lane & 3) * 8;   // 0,8,16,24
  // per-wave chunk list: c = wv + 4*i; c<ACH -> A rows, else W rows
  const unsigned short* gbase[CPW];
#pragma unroll
  for (int i = 0; i < CPW; i++) {
    int c = wv + i * 4;
    gbase[i] = (c < ACH)
        ? A + (size_t)(m0 + c * 16 + lrow) * Kd + lcol
        : W + (size_t)(n0 + (c - ACH) * 16 + lrow) * Kd + lcol;
  }
  auto stage = [&](int buf, int k0) {
#pragma unroll
    for (int i = 0; i < CPW; i++) {
      int c = wv + i * 4;
      gld16(gbase[i] + k0, &S[buf][c * 512]);
    }
  };
  stage(0, 0);
  drain_dma_then_barrier();  // buf0 ready for all waves
  int cur = 0;
  for (int k0 = 0; k0 < Kd; k0 += 32) {
    int nxt = cur ^ 1;
    if (k0 + 32 < Kd) stage(nxt, k0 + 32);  // async prefetch overlaps MFMA below
    const unsigned short* Sa = &S[cur][0];
    const unsigned short* Sb = &S[cur][BM * 32];
    short8 af[MI], bf[4];
#pragma unroll
    for (int i = 0; i < MI; i++)
      af[i] = *reinterpret_cast<const short8*>(
          &Sa[(wm * (BM / 2) + i * 16 + lr) * 32 + lg * 8]);
#pragma unroll
    for (int i = 0; i < 4; i++)
      bf[i] = *reinterpret_cast<const short8*>(
          &Sb[(wn * 64 + i * 16 + lr) * 32 + lg * 8]);
#pragma unroll
    for (int mi = 0; mi < MI; mi++)
#pragma unroll
      for (int ni = 0; ni < 4; ni++)
        acc[mi][ni] = MFMA16(af[mi], bf[ni], acc[mi][ni]);
    drain_dma_then_barrier();  // publish nxt (DMA done) + protect overwrite
    cur = nxt;
  }
  int row0 = m0 + wm * (BM / 2), col0 = n0 + wn * 64;
#pragma unroll
  for (int mi = 0; mi < MI; mi++)
#pragma unroll
    for (int ni = 0; ni < 4; ni++) {
      int col = col0 + ni * 16 + lr;
      int rbase = row0 + mi * 16 + lg * 4;
      for (int i = 0; i < 4; i++) {
        int row = rbase + i;
        float v = acc[mi][ni][i];
        if (MODE == 0) {
          outF[(size_t)row * Nn + col] = v;
        } else if (MODE == 1) {
          outF[(size_t)row * Nn + col] =
              resid[(size_t)row * Nn + col] + gamma[col] * (v + bias[col]);
        } else {
          float t = v + bias[col];
          float g = 0.5f * t * (1.f + erff(t * 0.70710678f));
          outB[(size_t)row * Nn + col] = f2b(g);
        }
      }
    }
}

extern "C" void kernel_launch(void* const* d_in, const int* in_sizes, int n_in,
                              void* d_out, int out_size, void* d_ws, size_t ws_size,
                              hipStream_t stream) {
  const float* x      = (const float*)d_in[0];
  const float* relb   = (const float*)d_in[1];
  const float* qkv_w  = (const float*)d_in[2];
  const float* qnw    = (const float*)d_in[3];
  const float* qnb    = (const float*)d_in[4];
  const float* knw    = (const float*)d_in[5];
  const float* knb    = (const float*)d_in[6];
  const float* proj_w = (const float*)d_in[7];
  const float* proj_b = (const float*)d_in[8];
  const float* n1w    = (const float*)d_in[9];
  const float* n1b    = (const float*)d_in[10];
  const float* n2w    = (const float*)d_in[11];
  const float* n2b    = (const float*)d_in[12];
  const float* fc1_w  = (const float*)d_in[13];
  const float* fc1_b  = (const float*)d_in[14];
  const float* fc2_w  = (const float*)d_in[15];
  const float* fc2_b  = (const float*)d_in[16];
  const float* ls1    = (const float*)d_in[17];
  const float* ls2    = (const float*)d_in[18];
  float* out = (float*)d_out;

  char* ws = (char*)d_ws;
  size_t off = 0;
  auto take = [&](size_t bytes) {
    char* p = ws + off;
    off += (bytes + 255) & ~(size_t)255;
    return p;
  };
  unsigned short* h     = (unsigned short*)take((size_t)4096 * 1024 * 2);
  unsigned short* wqkv  = (unsigned short*)take((size_t)3072 * 1024 * 2);
  unsigned short* wproj = (unsigned short*)take((size_t)1024 * 1024 * 2);
  unsigned short* wfc1  = (unsigned short*)take((size_t)4096 * 1024 * 2);
  unsigned short* wfc2  = (unsigned short*)take((size_t)4096 * 1024 * 2);
  float*          qkvb  = (float*)take((size_t)4096 * 3072 * 4);
  unsigned short* Q     = (unsigned short*)take((size_t)64 * 1024 * 64 * 2);
  unsigned short* Kb    = (unsigned short*)take((size_t)64 * 1024 * 64 * 2);
  unsigned short* Vt    = (unsigned short*)take((size_t)64 * 64 * 1024 * 2);
  unsigned short* ao    = (unsigned short*)take((size_t)4096 * 1024 * 2);
  float*          x1    = (float*)take((size_t)4096 * 1024 * 4);
  unsigned short* h2 = h;                      // reuse (h dead after QKV GEMM)
  unsigned short* m1 = (unsigned short*)qkvb;  // reuse (qkv dead after pack; 32MB<=48MB)

  cvt_bf16_kernel<<<1024, 256, 0, stream>>>(qkv_w, wqkv, 3072 * 1024 / 4);
  cvt_bf16_kernel<<<1024, 256, 0, stream>>>(proj_w, wproj, 1024 * 1024 / 4);
  cvt_bf16_kernel<<<1024, 256, 0, stream>>>(fc1_w, wfc1, 4096 * 1024 / 4);
  cvt_bf16_kernel<<<1024, 256, 0, stream>>>(fc2_w, wfc2, 4096 * 1024 / 4);

  ln_kernel<<<4096, 256, 0, stream>>>(x, n1w, n1b, h);
  // QKV: 4096x3072x1024, BM=128 -> grid 24*32=768 (%8==0)
  gemm_bt<0, 128><<<768, 256, 0, stream>>>(h, wqkv, nullptr, nullptr, nullptr,
                                           qkvb, nullptr, 4096, 3072, 1024);
  qkpack_kernel<<<16384, 256, 0, stream>>>(qkvb, qnw, qnb, knw, knb, Q, Kb, Vt);
  attn_kernel<<<1024, 256, 0, stream>>>(Q, Kb, Vt, relb, ao);
  // proj: 4096x1024x1024, BM=64 -> grid 8*64=512 (2 blocks/CU)
  gemm_bt<1, 64><<<512, 256, 0, stream>>>(ao, wproj, proj_b, x, ls1, x1,
                                          nullptr, 4096, 1024, 1024);
  ln_kernel<<<4096, 256, 0, stream>>>(x1, n2w, n2b, h2);
  // FC1: 4096x4096x1024, BM=128 -> grid 32*32=1024
  gemm_bt<2, 128><<<1024, 256, 0, stream>>>(h2, wfc1, fc1_b, nullptr, nullptr,
                                            nullptr, m1, 4096, 4096, 1024);
  // FC2: 4096x1024x4096, BM=64 -> grid 8*64=512
  gemm_bt<1, 64><<<512, 256, 0, stream>>>(m1, wfc2, fc2_b, x1, ls2, out,
                                          nullptr, 4096, 1024, 4096);
}

// Round 8
// 446.185 us; speedup vs baseline: 1.1564x; 1.0665x over previous
//
#include <hip/hip_runtime.h>
#include <hip/hip_bf16.h>

// RelPosBlock: LN1 -> QKV -> per-head QK-LN -> attn(+rel_bias) -> proj(+LS1, resid)
//              -> LN2 -> FC1+GELU -> FC2(+LS2, resid)
// B=4 N=1024 C=1024 H=16 D=64 Hid=4096, all inputs f32, output f32.

typedef __attribute__((ext_vector_type(8))) short short8;   // 8 bf16 (4 VGPR)
typedef __attribute__((ext_vector_type(4))) float f32x4;

#define MFMA16(a, b, c) __builtin_amdgcn_mfma_f32_16x16x32_bf16(a, b, c, 0, 0, 0)

static __device__ __forceinline__ unsigned short f2b(float f) {
  union { __hip_bfloat16 h; unsigned short u; } cv;
  cv.h = __float2bfloat16(f);
  return cv.u;
}

// async global->LDS, 16B per lane; lds base must be wave-uniform (HW adds lane*16)
static __device__ __forceinline__ void gld16(const unsigned short* g,
                                             unsigned short* l) {
  __builtin_amdgcn_global_load_lds(
      (const __attribute__((address_space(1))) void*)g,
      (__attribute__((address_space(3))) void*)l, 16, 0, 0);
}

// explicit DMA drain: do NOT trust __syncthreads to emit vmcnt(0) when the
// stage is separated from the barrier by compute (round-6 race post-mortem).
static __device__ __forceinline__ void drain_dma_then_barrier() {
  asm volatile("s_waitcnt vmcnt(0)" ::: "memory");
  __builtin_amdgcn_sched_barrier(0);
  __syncthreads();
}

// ---------------- f32 -> bf16 convert (grid-stride, float4) ----------------
__global__ void cvt_bf16_kernel(const float* __restrict__ in,
                                unsigned short* __restrict__ out, int n4) {
  int i = blockIdx.x * blockDim.x + threadIdx.x;
  int stride = gridDim.x * blockDim.x;
  for (; i < n4; i += stride) {
    float4 v = reinterpret_cast<const float4*>(in)[i];
    ushort4 o;
    o.x = f2b(v.x); o.y = f2b(v.y); o.z = f2b(v.z); o.w = f2b(v.w);
    reinterpret_cast<ushort4*>(out)[i] = o;
  }
}

// ---------------- LayerNorm over C=1024, f32 in -> bf16 out ----------------
__global__ __launch_bounds__(256) void ln_kernel(const float* __restrict__ x,
                                                 const float* __restrict__ w,
                                                 const float* __restrict__ b,
                                                 unsigned short* __restrict__ out) {
  int row = blockIdx.x, tid = threadIdx.x;
  const float* xr = x + (size_t)row * 1024;
  float4 v = reinterpret_cast<const float4*>(xr)[tid];
  float s = v.x + v.y + v.z + v.w;
  float s2 = v.x * v.x + v.y * v.y + v.z * v.z + v.w * v.w;
  for (int off = 1; off < 64; off <<= 1) {
    s += __shfl_xor(s, off);
    s2 += __shfl_xor(s2, off);
  }
  __shared__ float red[8];
  int wid = tid >> 6;
  if ((tid & 63) == 0) { red[wid] = s; red[4 + wid] = s2; }
  __syncthreads();
  s = red[0] + red[1] + red[2] + red[3];
  s2 = red[4] + red[5] + red[6] + red[7];
  float mean = s * (1.f / 1024.f);
  float rs = rsqrtf(s2 * (1.f / 1024.f) - mean * mean + 1e-5f);
  float4 wv = reinterpret_cast<const float4*>(w)[tid];
  float4 bv = reinterpret_cast<const float4*>(b)[tid];
  ushort4 o;
  o.x = f2b((v.x - mean) * rs * wv.x + bv.x);
  o.y = f2b((v.y - mean) * rs * wv.y + bv.y);
  o.z = f2b((v.z - mean) * rs * wv.z + bv.z);
  o.w = f2b((v.w - mean) * rs * wv.w + bv.w);
  reinterpret_cast<ushort4*>(out + (size_t)row * 1024)[tid] = o;
}

// ------------- per-head Q/K LayerNorm (D=64) + pack Q,K,Vt bf16 -------------
// qkv f32 [4096][3072], j = qkvi*1024 + h*64 + d
// Q,K: [B*H, N, 64] bf16 (Q pre-scaled by D^-0.5); Vt: [B*H, 64, N] bf16
__global__ __launch_bounds__(256) void qkpack_kernel(
    const float* __restrict__ qkv, const float* __restrict__ qw,
    const float* __restrict__ qb, const float* __restrict__ kw,
    const float* __restrict__ kb_, unsigned short* __restrict__ Q,
    unsigned short* __restrict__ K, unsigned short* __restrict__ Vt) {
  int wid = blockIdx.x * 4 + (threadIdx.x >> 6);
  int lane = threadIdx.x & 63;
  int m = wid >> 4;  // 0..4095
  int h = wid & 15;
  int b = m >> 10, n = m & 1023;
  const float* base = qkv + (size_t)m * 3072 + h * 64 + lane;
  float q = base[0], k = base[1024], v = base[2048];
  float qs = q, qs2 = q * q, ks = k, ks2 = k * k;
  for (int off = 1; off < 64; off <<= 1) {
    qs += __shfl_xor(qs, off); qs2 += __shfl_xor(qs2, off);
    ks += __shfl_xor(ks, off); ks2 += __shfl_xor(ks2, off);
  }
  float qm = qs * (1.f / 64.f), qv = qs2 * (1.f / 64.f) - qm * qm;
  float km = ks * (1.f / 64.f), kv = ks2 * (1.f / 64.f) - km * km;
  float qn = (q - qm) * rsqrtf(qv + 1e-5f) * qw[lane] + qb[lane];
  float kn = (k - km) * rsqrtf(kv + 1e-5f) * kw[lane] + kb_[lane];
  int bh = b * 16 + h;
  Q[((size_t)bh * 1024 + n) * 64 + lane] = f2b(qn * 0.125f);
  K[((size_t)bh * 1024 + n) * 64 + lane] = f2b(kn);
  Vt[((size_t)bh * 64 + lane) * 1024 + n] = f2b(v);
}

// ---------------- flash attention with rel_bias ----------------
// grid: [B*H*16], block 256 (4 waves x 16 q-rows). 32-key tiles.
// T14 register-prefetch of K/V and bias (issue kt+1's loads during kt's
// compute); per-lane partial softmax sum (one 16-lane reduce after loop).
__global__ __launch_bounds__(256) void attn_kernel(
    const unsigned short* __restrict__ Q, const unsigned short* __restrict__ K,
    const unsigned short* __restrict__ Vt, const float* __restrict__ rb,
    unsigned short* __restrict__ O) {
  __shared__ unsigned short Ks[32][72];     // 32 keys x 64 chans (stride 72: 2-way banks)
  __shared__ unsigned short Vs[64][40];     // 64 d x 32 keys (+pad)
  __shared__ unsigned short Ps[4][16][40];  // per-wave P tile 16x32 (+pad)
  int bid = blockIdx.x;
  int qt = bid & 15, bh = bid >> 4;
  int h = bh & 15, b = bh >> 4;
  int q0 = qt * 64;
  int tid = threadIdx.x, lane = tid & 63, w = tid >> 6;
  int lg = lane >> 4, lr = lane & 15;

  short8 qf[2];
  {
    int qrow = q0 + w * 16 + lr;
    const unsigned short* qp = Q + ((size_t)bh * 1024 + qrow) * 64;
    qf[0] = *reinterpret_cast<const short8*>(qp + lg * 8);
    qf[1] = *reinterpret_cast<const short8*>(qp + 32 + lg * 8);
  }
  f32x4 o[4] = {};
  float mrow[4], lsum[4];
  for (int i = 0; i < 4; i++) { mrow[i] = -1e30f; lsum[i] = 0.f; }
  const float* rbh = rb + (size_t)h * 1024 * 1024;
  int myrow = q0 + w * 16 + lg * 4;

  // staging coords + prologue register prefetch for kt=0
  int kr = tid >> 3, kc = (tid & 7) * 8;
  int vd = tid >> 2, vj = (tid & 3) * 8;
  const unsigned short* Kbase = K + ((size_t)bh * 1024 + kr) * 64 + kc;
  const unsigned short* Vbase = Vt + ((size_t)bh * 64 + vd) * 1024 + vj;
  short8 kreg = *reinterpret_cast<const short8*>(Kbase);
  short8 vreg = *reinterpret_cast<const short8*>(Vbase);
  float bpf[8];
#pragma unroll
  for (int i = 0; i < 4; i++) {
    const float* bp = rbh + (size_t)(myrow + i) * 1024 + lr;
    bpf[i] = bp[0];
    bpf[4 + i] = bp[16];
  }

  for (int kt = 0; kt < 32; kt++) {
    int ktn = kt < 31 ? kt + 1 : 31;  // clamped (tail reloads, harmless)
    __syncthreads();  // prev iteration's Ks/Vs reads done before overwrite
    *reinterpret_cast<short8*>(&Ks[kr][kc]) = kreg;
    *reinterpret_cast<short8*>(&Vs[vd][vj]) = vreg;
    // issue next tile's K/V loads now: latency hides under this iter's compute
    kreg = *reinterpret_cast<const short8*>(Kbase + (size_t)ktn * 2048);
    vreg = *reinterpret_cast<const short8*>(Vbase + ktn * 32);
    __syncthreads();  // publish Ks/Vs (plain ds_write drain: safe)
    // rotate bias regs, then issue next tile's bias loads
    float bcur[8];
#pragma unroll
    for (int i = 0; i < 8; i++) bcur[i] = bpf[i];
#pragma unroll
    for (int i = 0; i < 4; i++) {
      const float* bp = rbh + (size_t)(myrow + i) * 1024 + ktn * 32 + lr;
      bpf[i] = bp[0];
      bpf[4 + i] = bp[16];
    }
    // S = Q K^T  (two 16-key subtiles)
    f32x4 s[2] = {};
#pragma unroll
    for (int t = 0; t < 2; t++) {
      short8 kf0 = *reinterpret_cast<const short8*>(&Ks[t * 16 + lr][lg * 8]);
      short8 kf1 = *reinterpret_cast<const short8*>(&Ks[t * 16 + lr][32 + lg * 8]);
      s[t] = MFMA16(qf[0], kf0, s[t]);
      s[t] = MFMA16(qf[1], kf1, s[t]);
    }
    // online softmax (C-frag: col=lane&15, row=(lane>>4)*4+i)
#pragma unroll
    for (int i = 0; i < 4; i++) {
      float s0 = s[0][i] + bcur[i];
      float s1 = s[1][i] + bcur[4 + i];
      float mx = fmaxf(s0, s1);
      for (int off = 1; off < 16; off <<= 1) mx = fmaxf(mx, __shfl_xor(mx, off));
      float mnew = fmaxf(mrow[i], mx);
      float corr = __expf(mrow[i] - mnew);
      float p0 = __expf(s0 - mnew), p1 = __expf(s1 - mnew);
      lsum[i] = lsum[i] * corr + p0 + p1;  // per-lane partial (corr group-uniform)
      mrow[i] = mnew;
      for (int nd = 0; nd < 4; nd++) o[nd][i] *= corr;
      Ps[w][lg * 4 + i][lr] = f2b(p0);
      Ps[w][lg * 4 + i][16 + lr] = f2b(p1);
    }
    __syncthreads();  // make cross-lane P writes visible (and order vs ds reads)
    // O += P V  (A-frag of P: row=lane&15, k=(lane>>4)*8+i)
    short8 pa = *reinterpret_cast<const short8*>(&Ps[w][lr][lg * 8]);
#pragma unroll
    for (int nd = 0; nd < 4; nd++) {
      short8 vf = *reinterpret_cast<const short8*>(&Vs[nd * 16 + lr][lg * 8]);
      o[nd] = MFMA16(pa, vf, o[nd]);
    }
  }
  // final 16-lane reduction of the per-lane partial sums (once, not per tile)
#pragma unroll
  for (int i = 0; i < 4; i++) {
    float t = lsum[i];
    for (int off = 1; off < 16; off <<= 1) t += __shfl_xor(t, off);
    lsum[i] = t;
  }
  // write O: [B,N,H*64] bf16
#pragma unroll
  for (int i = 0; i < 4; i++) {
    float inv = 1.f / lsum[i];
    int n = q0 + w * 16 + lg * 4 + i;
    size_t base = ((size_t)(b * 1024 + n)) * 1024 + h * 64;
    for (int nd = 0; nd < 4; nd++) O[base + nd * 16 + lr] = f2b(o[nd][i] * inv);
  }
}

// ---------------- bf16 GEMM, B^T layout: out[m][n] = sum_k A[m][k]*W[n][k] ----------------
// BM x 128 tile, BK=32, 2-phase double-buffered linear LDS + global_load_lds w16,
// bijective XCD swizzle (grid must be %8==0; launched 1-D).
// Explicit vmcnt(0) drain before each publishing barrier (round-6 race fix).
// MODE 0: outF = acc                       (QKV)
// MODE 1: outF = resid + gamma*(acc+bias)  (proj / FC2 epilogue)
// MODE 2: outB = bf16(gelu(acc+bias))      (FC1)
template <int MODE, int BM>
__global__ __launch_bounds__(256) void gemm_bt(
    const unsigned short* __restrict__ A, const unsigned short* __restrict__ W,
    const float* __restrict__ bias, const float* __restrict__ resid,
    const float* __restrict__ gamma, float* __restrict__ outF,
    unsigned short* __restrict__ outB, int M, int Nn, int Kd) {
  constexpr int BN = 128;
  constexpr int MI = BM / 32;      // 16x16 A-frags per wave (wave covers BM/2 rows)
  constexpr int ACH = BM / 16;     // 1024B A-chunks per K-step
  constexpr int TCH = ACH + BN / 16;  // total chunks (16 or 12)
  constexpr int CPW = TCH / 4;     // chunks per wave (4 or 3)
  __shared__ unsigned short S[2][(BM + BN) * 32];  // A rows then W rows, 64B/row
  int tid = threadIdx.x;
  int lane = tid & 63, wv = tid >> 6;
  int wm = wv >> 1, wn = wv & 1;
  int lg = lane >> 4, lr = lane & 15;
  // XCD swizzle: contiguous chunk of block-ids per XCD (gridDim.x % 8 == 0)
  int nbx = Nn >> 7;
  int cpx = gridDim.x >> 3;
  int swz = (blockIdx.x & 7) * cpx + (blockIdx.x >> 3);
  int m0 = (swz / nbx) * BM, n0 = (swz % nbx) * BN;
  f32x4 acc[MI][4] = {};
  int lrow = lane >> 2;        // 0..15 within chunk
  int lcol = (lane & 3) * 8;   // 0,8,16,24
  // per-wave chunk list: c = wv + 4*i; c<ACH -> A rows, else W rows
  const unsigned short* gbase[CPW];
#pragma unroll
  for (int i = 0; i < CPW; i++) {
    int c = wv + i * 4;
    gbase[i] = (c < ACH)
        ? A + (size_t)(m0 + c * 16 + lrow) * Kd + lcol
        : W + (size_t)(n0 + (c - ACH) * 16 + lrow) * Kd + lcol;
  }
  auto stage = [&](int buf, int k0) {
#pragma unroll
    for (int i = 0; i < CPW; i++) {
      int c = wv + i * 4;
      gld16(gbase[i] + k0, &S[buf][c * 512]);
    }
  };
  stage(0, 0);
  drain_dma_then_barrier();  // buf0 ready for all waves
  int cur = 0;
  for (int k0 = 0; k0 < Kd; k0 += 32) {
    int nxt = cur ^ 1;
    if (k0 + 32 < Kd) stage(nxt, k0 + 32);  // async prefetch overlaps MFMA below
    const unsigned short* Sa = &S[cur][0];
    const unsigned short* Sb = &S[cur][BM * 32];
    short8 af[MI], bf[4];
#pragma unroll
    for (int i = 0; i < MI; i++)
      af[i] = *reinterpret_cast<const short8*>(
          &Sa[(wm * (BM / 2) + i * 16 + lr) * 32 + lg * 8]);
#pragma unroll
    for (int i = 0; i < 4; i++)
      bf[i] = *reinterpret_cast<const short8*>(
          &Sb[(wn * 64 + i * 16 + lr) * 32 + lg * 8]);
#pragma unroll
    for (int mi = 0; mi < MI; mi++)
#pragma unroll
      for (int ni = 0; ni < 4; ni++)
        acc[mi][ni] = MFMA16(af[mi], bf[ni], acc[mi][ni]);
    drain_dma_then_barrier();  // publish nxt (DMA done) + protect overwrite
    cur = nxt;
  }
  int row0 = m0 + wm * (BM / 2), col0 = n0 + wn * 64;
#pragma unroll
  for (int mi = 0; mi < MI; mi++)
#pragma unroll
    for (int ni = 0; ni < 4; ni++) {
      int col = col0 + ni * 16 + lr;
      int rbase = row0 + mi * 16 + lg * 4;
      for (int i = 0; i < 4; i++) {
        int row = rbase + i;
        float v = acc[mi][ni][i];
        if (MODE == 0) {
          outF[(size_t)row * Nn + col] = v;
        } else if (MODE == 1) {
          outF[(size_t)row * Nn + col] =
              resid[(size_t)row * Nn + col] + gamma[col] * (v + bias[col]);
        } else {
          float t = v + bias[col];
          float g = 0.5f * t * (1.f + erff(t * 0.70710678f));
          outB[(size_t)row * Nn + col] = f2b(g);
        }
      }
    }
}

extern "C" void kernel_launch(void* const* d_in, const int* in_sizes, int n_in,
                              void* d_out, int out_size, void* d_ws, size_t ws_size,
                              hipStream_t stream) {
  const float* x      = (const float*)d_in[0];
  const float* relb   = (const float*)d_in[1];
  const float* qkv_w  = (const float*)d_in[2];
  const float* qnw    = (const float*)d_in[3];
  const float* qnb    = (const float*)d_in[4];
  const float* knw    = (const float*)d_in[5];
  const float* knb    = (const float*)d_in[6];
  const float* proj_w = (const float*)d_in[7];
  const float* proj_b = (const float*)d_in[8];
  const float* n1w    = (const float*)d_in[9];
  const float* n1b    = (const float*)d_in[10];
  const float* n2w    = (const float*)d_in[11];
  const float* n2b    = (const float*)d_in[12];
  const float* fc1_w  = (const float*)d_in[13];
  const float* fc1_b  = (const float*)d_in[14];
  const float* fc2_w  = (const float*)d_in[15];
  const float* fc2_b  = (const float*)d_in[16];
  const float* ls1    = (const float*)d_in[17];
  const float* ls2    = (const float*)d_in[18];
  float* out = (float*)d_out;

  char* ws = (char*)d_ws;
  size_t off = 0;
  auto take = [&](size_t bytes) {
    char* p = ws + off;
    off += (bytes + 255) & ~(size_t)255;
    return p;
  };
  unsigned short* h     = (unsigned short*)take((size_t)4096 * 1024 * 2);
  unsigned short* wqkv  = (unsigned short*)take((size_t)3072 * 1024 * 2);
  unsigned short* wproj = (unsigned short*)take((size_t)1024 * 1024 * 2);
  unsigned short* wfc1  = (unsigned short*)take((size_t)4096 * 1024 * 2);
  unsigned short* wfc2  = (unsigned short*)take((size_t)4096 * 1024 * 2);
  float*          qkvb  = (float*)take((size_t)4096 * 3072 * 4);
  unsigned short* Q     = (unsigned short*)take((size_t)64 * 1024 * 64 * 2);
  unsigned short* Kb    = (unsigned short*)take((size_t)64 * 1024 * 64 * 2);
  unsigned short* Vt    = (unsigned short*)take((size_t)64 * 64 * 1024 * 2);
  unsigned short* ao    = (unsigned short*)take((size_t)4096 * 1024 * 2);
  float*          x1    = (float*)take((size_t)4096 * 1024 * 4);
  unsigned short* h2 = h;                      // reuse (h dead after QKV GEMM)
  unsigned short* m1 = (unsigned short*)qkvb;  // reuse (qkv dead after pack; 32MB<=48MB)

  cvt_bf16_kernel<<<1024, 256, 0, stream>>>(qkv_w, wqkv, 3072 * 1024 / 4);
  cvt_bf16_kernel<<<1024, 256, 0, stream>>>(proj_w, wproj, 1024 * 1024 / 4);
  cvt_bf16_kernel<<<1024, 256, 0, stream>>>(fc1_w, wfc1, 4096 * 1024 / 4);
  cvt_bf16_kernel<<<1024, 256, 0, stream>>>(fc2_w, wfc2, 4096 * 1024 / 4);

  ln_kernel<<<4096, 256, 0, stream>>>(x, n1w, n1b, h);
  // QKV: 4096x3072x1024, BM=128 -> grid 24*32=768 (%8==0)
  gemm_bt<0, 128><<<768, 256, 0, stream>>>(h, wqkv, nullptr, nullptr, nullptr,
                                           qkvb, nullptr, 4096, 3072, 1024);
  qkpack_kernel<<<16384, 256, 0, stream>>>(qkvb, qnw, qnb, knw, knb, Q, Kb, Vt);
  attn_kernel<<<1024, 256, 0, stream>>>(Q, Kb, Vt, relb, ao);
  // proj: 4096x1024x1024, BM=64 -> grid 8*64=512 (2 blocks/CU)
  gemm_bt<1, 64><<<512, 256, 0, stream>>>(ao, wproj, proj_b, x, ls1, x1,
                                          nullptr, 4096, 1024, 1024);
  ln_kernel<<<4096, 256, 0, stream>>>(x1, n2w, n2b, h2);
  // FC1: 4096x4096x1024, BM=128 -> grid 32*32=1024
  gemm_bt<2, 128><<<1024, 256, 0, stream>>>(h2, wfc1, fc1_b, nullptr, nullptr,
                                            nullptr, m1, 4096, 4096, 1024);
  // FC2: 4096x1024x4096, BM=64 -> grid 8*64=512
  gemm_bt<1, 64><<<512, 256, 0, stream>>>(m1, wfc2, fc2_b, x1, ls2, out,
                                          nullptr, 4096, 1024, 4096);
}

// Round 10
// 441.057 us; speedup vs baseline: 1.1698x; 1.0116x over previous
//
#include <hip/hip_runtime.h>
#include <hip/hip_bf16.h>

// RelPosBlock: LN1 -> QKV -> per-head QK-LN -> attn(+rel_bias) -> proj(+LS1, resid)
//              -> LN2 -> FC1+GELU -> FC2(+LS2, resid)
// B=4 N=1024 C=1024 H=16 D=64 Hid=4096, all inputs f32, output f32.

typedef __attribute__((ext_vector_type(8))) short short8;   // 8 bf16 (4 VGPR)
typedef __attribute__((ext_vector_type(4))) float f32x4;

#define MFMA16(a, b, c) __builtin_amdgcn_mfma_f32_16x16x32_bf16(a, b, c, 0, 0, 0)

static __device__ __forceinline__ unsigned short f2b(float f) {
  union { __hip_bfloat16 h; unsigned short u; } cv;
  cv.h = __float2bfloat16(f);
  return cv.u;
}

// async global->LDS, 16B per lane; lds base must be wave-uniform (HW adds lane*16)
static __device__ __forceinline__ void gld16(const unsigned short* g,
                                             unsigned short* l) {
  __builtin_amdgcn_global_load_lds(
      (const __attribute__((address_space(1))) void*)g,
      (__attribute__((address_space(3))) void*)l, 16, 0, 0);
}

// ---------------- f32 -> bf16 convert (grid-stride, float4) ----------------
__global__ void cvt_bf16_kernel(const float* __restrict__ in,
                                unsigned short* __restrict__ out, int n4) {
  int i = blockIdx.x * blockDim.x + threadIdx.x;
  int stride = gridDim.x * blockDim.x;
  for (; i < n4; i += stride) {
    float4 v = reinterpret_cast<const float4*>(in)[i];
    ushort4 o;
    o.x = f2b(v.x); o.y = f2b(v.y); o.z = f2b(v.z); o.w = f2b(v.w);
    reinterpret_cast<ushort4*>(out)[i] = o;
  }
}

// ---------------- LayerNorm over C=1024, f32 in -> bf16 out ----------------
__global__ __launch_bounds__(256) void ln_kernel(const float* __restrict__ x,
                                                 const float* __restrict__ w,
                                                 const float* __restrict__ b,
                                                 unsigned short* __restrict__ out) {
  int row = blockIdx.x, tid = threadIdx.x;
  const float* xr = x + (size_t)row * 1024;
  float4 v = reinterpret_cast<const float4*>(xr)[tid];
  float s = v.x + v.y + v.z + v.w;
  float s2 = v.x * v.x + v.y * v.y + v.z * v.z + v.w * v.w;
  for (int off = 1; off < 64; off <<= 1) {
    s += __shfl_xor(s, off);
    s2 += __shfl_xor(s2, off);
  }
  __shared__ float red[8];
  int wid = tid >> 6;
  if ((tid & 63) == 0) { red[wid] = s; red[4 + wid] = s2; }
  __syncthreads();
  s = red[0] + red[1] + red[2] + red[3];
  s2 = red[4] + red[5] + red[6] + red[7];
  float mean = s * (1.f / 1024.f);
  float rs = rsqrtf(s2 * (1.f / 1024.f) - mean * mean + 1e-5f);
  float4 wv = reinterpret_cast<const float4*>(w)[tid];
  float4 bv = reinterpret_cast<const float4*>(b)[tid];
  ushort4 o;
  o.x = f2b((v.x - mean) * rs * wv.x + bv.x);
  o.y = f2b((v.y - mean) * rs * wv.y + bv.y);
  o.z = f2b((v.z - mean) * rs * wv.z + bv.z);
  o.w = f2b((v.w - mean) * rs * wv.w + bv.w);
  reinterpret_cast<ushort4*>(out + (size_t)row * 1024)[tid] = o;
}

// ------------- per-head Q/K LayerNorm (D=64) + pack Q,K,Vt bf16 -------------
// qkv f32 [4096][3072], j = qkvi*1024 + h*64 + d
// Q,K: [B*H, N, 64] bf16 (Q pre-scaled by D^-0.5); Vt: [B*H, 64, N] bf16
__global__ __launch_bounds__(256) void qkpack_kernel(
    const float* __restrict__ qkv, const float* __restrict__ qw,
    const float* __restrict__ qb, const float* __restrict__ kw,
    const float* __restrict__ kb_, unsigned short* __restrict__ Q,
    unsigned short* __restrict__ K, unsigned short* __restrict__ Vt) {
  int wid = blockIdx.x * 4 + (threadIdx.x >> 6);
  int lane = threadIdx.x & 63;
  int m = wid >> 4;  // 0..4095
  int h = wid & 15;
  int b = m >> 10, n = m & 1023;
  const float* base = qkv + (size_t)m * 3072 + h * 64 + lane;
  float q = base[0], k = base[1024], v = base[2048];
  float qs = q, qs2 = q * q, ks = k, ks2 = k * k;
  for (int off = 1; off < 64; off <<= 1) {
    qs += __shfl_xor(qs, off); qs2 += __shfl_xor(qs2, off);
    ks += __shfl_xor(ks, off); ks2 += __shfl_xor(ks2, off);
  }
  float qm = qs * (1.f / 64.f), qv = qs2 * (1.f / 64.f) - qm * qm;
  float km = ks * (1.f / 64.f), kv = ks2 * (1.f / 64.f) - km * km;
  float qn = (q - qm) * rsqrtf(qv + 1e-5f) * qw[lane] + qb[lane];
  float kn = (k - km) * rsqrtf(kv + 1e-5f) * kw[lane] + kb_[lane];
  int bh = b * 16 + h;
  Q[((size_t)bh * 1024 + n) * 64 + lane] = f2b(qn * 0.125f);
  K[((size_t)bh * 1024 + n) * 64 + lane] = f2b(kn);
  Vt[((size_t)bh * 64 + lane) * 1024 + n] = f2b(v);
}

// ---------------- flash attention with rel_bias ----------------
// grid: [B*H*16], block 256 (4 waves x 16 q-rows). 32-key tiles.
// T14 register-prefetch of K/V and bias (issue kt+1's loads during kt's
// compute); per-lane partial softmax sum (one 16-lane reduce after loop).
__global__ __launch_bounds__(256) void attn_kernel(
    const unsigned short* __restrict__ Q, const unsigned short* __restrict__ K,
    const unsigned short* __restrict__ Vt, const float* __restrict__ rb,
    unsigned short* __restrict__ O) {
  __shared__ unsigned short Ks[32][72];     // 32 keys x 64 chans (stride 72: 2-way banks)
  __shared__ unsigned short Vs[64][40];     // 64 d x 32 keys (+pad)
  __shared__ unsigned short Ps[4][16][40];  // per-wave P tile 16x32 (+pad)
  int bid = blockIdx.x;
  int qt = bid & 15, bh = bid >> 4;
  int h = bh & 15, b = bh >> 4;
  int q0 = qt * 64;
  int tid = threadIdx.x, lane = tid & 63, w = tid >> 6;
  int lg = lane >> 4, lr = lane & 15;

  short8 qf[2];
  {
    int qrow = q0 + w * 16 + lr;
    const unsigned short* qp = Q + ((size_t)bh * 1024 + qrow) * 64;
    qf[0] = *reinterpret_cast<const short8*>(qp + lg * 8);
    qf[1] = *reinterpret_cast<const short8*>(qp + 32 + lg * 8);
  }
  f32x4 o[4] = {};
  float mrow[4], lsum[4];
  for (int i = 0; i < 4; i++) { mrow[i] = -1e30f; lsum[i] = 0.f; }
  const float* rbh = rb + (size_t)h * 1024 * 1024;
  int myrow = q0 + w * 16 + lg * 4;

  // staging coords + prologue register prefetch for kt=0
  int kr = tid >> 3, kc = (tid & 7) * 8;
  int vd = tid >> 2, vj = (tid & 3) * 8;
  const unsigned short* Kbase = K + ((size_t)bh * 1024 + kr) * 64 + kc;
  const unsigned short* Vbase = Vt + ((size_t)bh * 64 + vd) * 1024 + vj;
  short8 kreg = *reinterpret_cast<const short8*>(Kbase);
  short8 vreg = *reinterpret_cast<const short8*>(Vbase);
  float bpf[8];
#pragma unroll
  for (int i = 0; i < 4; i++) {
    const float* bp = rbh + (size_t)(myrow + i) * 1024 + lr;
    bpf[i] = bp[0];
    bpf[4 + i] = bp[16];
  }

  for (int kt = 0; kt < 32; kt++) {
    int ktn = kt < 31 ? kt + 1 : 31;  // clamped (tail reloads, harmless)
    __syncthreads();  // prev iteration's Ks/Vs reads done before overwrite
    *reinterpret_cast<short8*>(&Ks[kr][kc]) = kreg;
    *reinterpret_cast<short8*>(&Vs[vd][vj]) = vreg;
    // issue next tile's K/V loads now: latency hides under this iter's compute
    kreg = *reinterpret_cast<const short8*>(Kbase + (size_t)ktn * 2048);
    vreg = *reinterpret_cast<const short8*>(Vbase + ktn * 32);
    __syncthreads();  // publish Ks/Vs (plain ds_write drain: safe)
    // rotate bias regs, then issue next tile's bias loads
    float bcur[8];
#pragma unroll
    for (int i = 0; i < 8; i++) bcur[i] = bpf[i];
#pragma unroll
    for (int i = 0; i < 4; i++) {
      const float* bp = rbh + (size_t)(myrow + i) * 1024 + ktn * 32 + lr;
      bpf[i] = bp[0];
      bpf[4 + i] = bp[16];
    }
    // S = Q K^T  (two 16-key subtiles)
    f32x4 s[2] = {};
#pragma unroll
    for (int t = 0; t < 2; t++) {
      short8 kf0 = *reinterpret_cast<const short8*>(&Ks[t * 16 + lr][lg * 8]);
      short8 kf1 = *reinterpret_cast<const short8*>(&Ks[t * 16 + lr][32 + lg * 8]);
      s[t] = MFMA16(qf[0], kf0, s[t]);
      s[t] = MFMA16(qf[1], kf1, s[t]);
    }
    // online softmax (C-frag: col=lane&15, row=(lane>>4)*4+i)
#pragma unroll
    for (int i = 0; i < 4; i++) {
      float s0 = s[0][i] + bcur[i];
      float s1 = s[1][i] + bcur[4 + i];
      float mx = fmaxf(s0, s1);
      for (int off = 1; off < 16; off <<= 1) mx = fmaxf(mx, __shfl_xor(mx, off));
      float mnew = fmaxf(mrow[i], mx);
      float corr = __expf(mrow[i] - mnew);
      float p0 = __expf(s0 - mnew), p1 = __expf(s1 - mnew);
      lsum[i] = lsum[i] * corr + p0 + p1;  // per-lane partial (corr group-uniform)
      mrow[i] = mnew;
      for (int nd = 0; nd < 4; nd++) o[nd][i] *= corr;
      Ps[w][lg * 4 + i][lr] = f2b(p0);
      Ps[w][lg * 4 + i][16 + lr] = f2b(p1);
    }
    __syncthreads();  // make cross-lane P writes visible (and order vs ds reads)
    // O += P V  (A-frag of P: row=lane&15, k=(lane>>4)*8+i)
    short8 pa = *reinterpret_cast<const short8*>(&Ps[w][lr][lg * 8]);
#pragma unroll
    for (int nd = 0; nd < 4; nd++) {
      short8 vf = *reinterpret_cast<const short8*>(&Vs[nd * 16 + lr][lg * 8]);
      o[nd] = MFMA16(pa, vf, o[nd]);
    }
  }
  // final 16-lane reduction of the per-lane partial sums (once, not per tile)
#pragma unroll
  for (int i = 0; i < 4; i++) {
    float t = lsum[i];
    for (int off = 1; off < 16; off <<= 1) t += __shfl_xor(t, off);
    lsum[i] = t;
  }
  // write O: [B,N,H*64] bf16
#pragma unroll
  for (int i = 0; i < 4; i++) {
    float inv = 1.f / lsum[i];
    int n = q0 + w * 16 + lg * 4 + i;
    size_t base = ((size_t)(b * 1024 + n)) * 1024 + h * 64;
    for (int nd = 0; nd < 4; nd++) O[base + nd * 16 + lr] = f2b(o[nd][i] * inv);
  }
}

// ---------------- bf16 GEMM, B^T layout: out[m][n] = sum_k A[m][k]*W[n][k] ----------------
// BM x 128 tile, BK=32, 3-buffer LDS ring + counted vmcnt (T4: loads span
// barriers, never drain to 0 mid-loop), global_load_lds w16, XCD swizzle.
// Ring safety: [vmcnt(CPW) -> barrier -> stage(t+2) -> ds_read/MFMA(t)]:
//   barrier orders all waves' compute(t-1) ds_reads BEFORE DMA into
//   buf[(t+2)%3]==buf[(t-1)%3]; per-wave vmcnt + barrier => stage(t) visible.
// MODE 0: outF = acc                       (QKV)
// MODE 1: outF = resid + gamma*(acc+bias)  (proj / FC2 epilogue)
// MODE 2: outB = bf16(gelu(acc+bias))      (FC1)
template <int MODE, int BM>
__global__ __launch_bounds__(256) void gemm_bt(
    const unsigned short* __restrict__ A, const unsigned short* __restrict__ W,
    const float* __restrict__ bias, const float* __restrict__ resid,
    const float* __restrict__ gamma, float* __restrict__ outF,
    unsigned short* __restrict__ outB, int M, int Nn, int Kd) {
  constexpr int BN = 128;
  constexpr int MI = BM / 32;      // 16x16 A-frags per wave (wave covers BM/2 rows)
  constexpr int ACH = BM / 16;     // 1024B A-chunks per K-step
  constexpr int TCH = ACH + BN / 16;  // total chunks (16 or 12)
  constexpr int CPW = TCH / 4;     // chunks per wave (4 or 3)
  __shared__ unsigned short S[3][(BM + BN) * 32];  // A rows then W rows, 64B/row
  int tid = threadIdx.x;
  int lane = tid & 63, wv = tid >> 6;
  int wm = wv >> 1, wn = wv & 1;
  int lg = lane >> 4, lr = lane & 15;
  // XCD swizzle: contiguous chunk of block-ids per XCD (gridDim.x % 8 == 0)
  int nbx = Nn >> 7;
  int cpx = gridDim.x >> 3;
  int swz = (blockIdx.x & 7) * cpx + (blockIdx.x >> 3);
  int m0 = (swz / nbx) * BM, n0 = (swz % nbx) * BN;
  f32x4 acc[MI][4] = {};
  int lrow = lane >> 2;        // 0..15 within chunk
  int lcol = (lane & 3) * 8;   // 0,8,16,24
  // per-wave chunk list: c = wv + 4*i; c<ACH -> A rows, else W rows
  const unsigned short* gbase[CPW];
#pragma unroll
  for (int i = 0; i < CPW; i++) {
    int c = wv + i * 4;
    gbase[i] = (c < ACH)
        ? A + (size_t)(m0 + c * 16 + lrow) * Kd + lcol
        : W + (size_t)(n0 + (c - ACH) * 16 + lrow) * Kd + lcol;
  }
  auto stage = [&](int buf, int k0) {
#pragma unroll
    for (int i = 0; i < CPW; i++) {
      int c = wv + i * 4;
      gld16(gbase[i] + k0, &S[buf][c * 512]);
    }
  };
  int NT = Kd >> 5;  // K-steps (>=32 for all our shapes)
  stage(0, 0);
  stage(1, 32);
  int cs = 0;  // buffer slot for compute step t
  for (int t = 0; t < NT; ++t) {
    // wait for MY stage(t) loads (leave stage(t+1)'s CPW in flight), then sync
    if (t + 1 < NT) {
      asm volatile("s_waitcnt vmcnt(%0)" ::"n"(CPW) : "memory");
    } else {
      asm volatile("s_waitcnt vmcnt(0)" ::: "memory");
    }
    __builtin_amdgcn_sched_barrier(0);
    __syncthreads();
    if (t + 2 < NT) {
      int s2 = cs + 2; if (s2 >= 3) s2 -= 3;
      stage(s2, (t + 2) * 32);
    }
    const unsigned short* Sa = &S[cs][0];
    const unsigned short* Sb = &S[cs][BM * 32];
    short8 af[MI], bf[4];
#pragma unroll
    for (int i = 0; i < MI; i++)
      af[i] = *reinterpret_cast<const short8*>(
          &Sa[(wm * (BM / 2) + i * 16 + lr) * 32 + lg * 8]);
#pragma unroll
    for (int i = 0; i < 4; i++)
      bf[i] = *reinterpret_cast<const short8*>(
          &Sb[(wn * 64 + i * 16 + lr) * 32 + lg * 8]);
#pragma unroll
    for (int mi = 0; mi < MI; mi++)
#pragma unroll
      for (int ni = 0; ni < 4; ni++)
        acc[mi][ni] = MFMA16(af[mi], bf[ni], acc[mi][ni]);
    cs = (cs + 1 == 3) ? 0 : cs + 1;
  }
  int row0 = m0 + wm * (BM / 2), col0 = n0 + wn * 64;
#pragma unroll
  for (int mi = 0; mi < MI; mi++)
#pragma unroll
    for (int ni = 0; ni < 4; ni++) {
      int col = col0 + ni * 16 + lr;
      int rbase = row0 + mi * 16 + lg * 4;
      for (int i = 0; i < 4; i++) {
        int row = rbase + i;
        float v = acc[mi][ni][i];
        if (MODE == 0) {
          outF[(size_t)row * Nn + col] = v;
        } else if (MODE == 1) {
          outF[(size_t)row * Nn + col] =
              resid[(size_t)row * Nn + col] + gamma[col] * (v + bias[col]);
        } else {
          float t = v + bias[col];
          float g = 0.5f * t * (1.f + erff(t * 0.70710678f));
          outB[(size_t)row * Nn + col] = f2b(g);
        }
      }
    }
}

extern "C" void kernel_launch(void* const* d_in, const int* in_sizes, int n_in,
                              void* d_out, int out_size, void* d_ws, size_t ws_size,
                              hipStream_t stream) {
  const float* x      = (const float*)d_in[0];
  const float* relb   = (const float*)d_in[1];
  const float* qkv_w  = (const float*)d_in[2];
  const float* qnw    = (const float*)d_in[3];
  const float* qnb    = (const float*)d_in[4];
  const float* knw    = (const float*)d_in[5];
  const float* knb    = (const float*)d_in[6];
  const float* proj_w = (const float*)d_in[7];
  const float* proj_b = (const float*)d_in[8];
  const float* n1w    = (const float*)d_in[9];
  const float* n1b    = (const float*)d_in[10];
  const float* n2w    = (const float*)d_in[11];
  const float* n2b    = (const float*)d_in[12];
  const float* fc1_w  = (const float*)d_in[13];
  const float* fc1_b  = (const float*)d_in[14];
  const float* fc2_w  = (const float*)d_in[15];
  const float* fc2_b  = (const float*)d_in[16];
  const float* ls1    = (const float*)d_in[17];
  const float* ls2    = (const float*)d_in[18];
  float* out = (float*)d_out;

  char* ws = (char*)d_ws;
  size_t off = 0;
  auto take = [&](size_t bytes) {
    char* p = ws + off;
    off += (bytes + 255) & ~(size_t)255;
    return p;
  };
  unsigned short* h     = (unsigned short*)take((size_t)4096 * 1024 * 2);
  unsigned short* wqkv  = (unsigned short*)take((size_t)3072 * 1024 * 2);
  unsigned short* wproj = (unsigned short*)take((size_t)1024 * 1024 * 2);
  unsigned short* wfc1  = (unsigned short*)take((size_t)4096 * 1024 * 2);
  unsigned short* wfc2  = (unsigned short*)take((size_t)4096 * 1024 * 2);
  float*          qkvb  = (float*)take((size_t)4096 * 3072 * 4);
  unsigned short* Q     = (unsigned short*)take((size_t)64 * 1024 * 64 * 2);
  unsigned short* Kb    = (unsigned short*)take((size_t)64 * 1024 * 64 * 2);
  unsigned short* Vt    = (unsigned short*)take((size_t)64 * 64 * 1024 * 2);
  unsigned short* ao    = (unsigned short*)take((size_t)4096 * 1024 * 2);
  float*          x1    = (float*)take((size_t)4096 * 1024 * 4);
  unsigned short* h2 = h;                      // reuse (h dead after QKV GEMM)
  unsigned short* m1 = (unsigned short*)qkvb;  // reuse (qkv dead after pack; 32MB<=48MB)

  cvt_bf16_kernel<<<1024, 256, 0, stream>>>(qkv_w, wqkv, 3072 * 1024 / 4);
  cvt_bf16_kernel<<<1024, 256, 0, stream>>>(proj_w, wproj, 1024 * 1024 / 4);
  cvt_bf16_kernel<<<1024, 256, 0, stream>>>(fc1_w, wfc1, 4096 * 1024 / 4);
  cvt_bf16_kernel<<<1024, 256, 0, stream>>>(fc2_w, wfc2, 4096 * 1024 / 4);

  ln_kernel<<<4096, 256, 0, stream>>>(x, n1w, n1b, h);
  // QKV: 4096x3072x1024, BM=128 -> grid 24*32=768 (%8==0)
  gemm_bt<0, 128><<<768, 256, 0, stream>>>(h, wqkv, nullptr, nullptr, nullptr,
                                           qkvb, nullptr, 4096, 3072, 1024);
  qkpack_kernel<<<16384, 256, 0, stream>>>(qkvb, qnw, qnb, knw, knb, Q, Kb, Vt);
  attn_kernel<<<1024, 256, 0, stream>>>(Q, Kb, Vt, relb, ao);
  // proj: 4096x1024x1024, BM=64 -> grid 8*64=512 (2 blocks/CU)
  gemm_bt<1, 64><<<512, 256, 0, stream>>>(ao, wproj, proj_b, x, ls1, x1,
                                          nullptr, 4096, 1024, 1024);
  ln_kernel<<<4096, 256, 0, stream>>>(x1, n2w, n2b, h2);
  // FC1: 4096x4096x1024, BM=128 -> grid 32*32=1024
  gemm_bt<2, 128><<<1024, 256, 0, stream>>>(h2, wfc1, fc1_b, nullptr, nullptr,
                                            nullptr, m1, 4096, 4096, 1024);
  // FC2: 4096x1024x4096, BM=64 -> grid 8*64=512
  gemm_bt<1, 64><<<512, 256, 0, stream>>>(m1, wfc2, fc2_b, x1, ls2, out,
                                          nullptr, 4096, 1024, 4096);
}